// Round 4
// baseline (276.150 us; speedup 1.0000x reference)
//
#include <hip/hip_runtime.h>
#include <hip/hip_bf16.h>
#include <hip/hip_cooperative_groups.h>
#include <math.h>

namespace cg = cooperative_groups;

#define CIN 256
#define COUT 512

typedef __attribute__((ext_vector_type(8))) short bf16x8;
typedef __attribute__((ext_vector_type(4))) float f32x4;
typedef __attribute__((ext_vector_type(4))) float f32x4v;

__device__ __forceinline__ ushort f2bf(float f) {
    union { float f; unsigned u; } x; x.f = f;
    unsigned r = x.u + 0x7FFFu + ((x.u >> 16) & 1u);   // RNE
    return (ushort)(r >> 16);
}

__device__ __forceinline__ int bsearch_eq(const int* __restrict__ arr, int n, int key) {
    int lo = 0, hi = n - 1;
    while (lo <= hi) {
        int mid = (lo + hi) >> 1;
        int v = arr[mid];
        if (v == key) return mid;
        if (v < key) lo = mid + 1; else hi = mid - 1;
    }
    return -1;
}

// ---------------------------------------------------------------------------
// Cooperative mega-kernel: pool + GEMM + BN-stats + grid-sync + BN-apply.
// grid = M/64 blocks (256), block = 512 threads (8 waves), 1 block/CU.
// Each block owns 64 pooled rows (m-tile) and the FULL 512-col range
// (wave w covers cols [w*64, w*64+64)).
// ---------------------------------------------------------------------------
__global__ __launch_bounds__(512, 2) void mega_kernel(
    const float* __restrict__ data,
    const float* __restrict__ W,
    const float* __restrict__ gamma,
    const float* __restrict__ beta,
    const int*   __restrict__ idx5, int n_i5,
    const int*   __restrict__ idx4, int n_i4,
    float* __restrict__ partial,     // [gridDim.x][1024]
    float* __restrict__ scaleg,      // [512]
    float* __restrict__ shiftg,      // [512]
    float* __restrict__ out,
    float invN, int rows_out)
{
    __shared__ __align__(16) union {
        ushort A[64 * 256];          // 32 KiB: pooled bf16 tile (swizzled)
        float  outb[16][516];        // 33 KiB: apply-phase staging
    } u;
    __shared__ int   inv5_l[512];
    __shared__ int   inv4_l[128];
    __shared__ float scl[512], sht[512], rsht[512];
    __shared__ float wred[16];

    const int b    = blockIdx.x;
    const int t    = threadIdx.x;
    const int lane = t & 63;
    const int w    = t >> 6;         // wave 0..7
    const int g0   = b * 64;         // first pooled row of this block
    const int orpb = rows_out / gridDim.x;   // out rows per block (128)

    // ---- phase 0: inverse maps via binary search on sorted idx arrays
    if (t < 512) inv5_l[t] = bsearch_eq(idx5, n_i5, g0 * 8 + t);
    if (t < 128) inv4_l[t] = bsearch_eq(idx4, n_i4, b * orpb + t);
    __syncthreads();

    // ---- phase 1: fused double max-pool, 8 rows per wave -> u.A (bf16, swizzled)
    for (int j = 0; j < 8; ++j) {
        int row = w * 8 + j;                  // 0..63 (local pooled row)
        float4 acc = make_float4(-INFINITY, -INFINITY, -INFINITY, -INFINITY);
        bool any_empty = false;
        #pragma unroll
        for (int s = 0; s < 8; ++s) {
            int i = inv5_l[row * 8 + s];
            i = __builtin_amdgcn_readfirstlane(i);    // wave-uniform
            if (i >= 0) {
                const float* base = data + (size_t)i * (8 * CIN) + lane * 4;
                #pragma unroll
                for (int r = 0; r < 8; ++r) {
                    f32x4v v = __builtin_nontemporal_load(
                        reinterpret_cast<const f32x4v*>(base + (size_t)r * CIN));
                    acc.x = fmaxf(acc.x, v.x);
                    acc.y = fmaxf(acc.y, v.y);
                    acc.z = fmaxf(acc.z, v.z);
                    acc.w = fmaxf(acc.w, v.w);
                }
            } else {
                any_empty = true;
            }
        }
        if (any_empty) {
            acc.x = fmaxf(acc.x, 0.f);
            acc.y = fmaxf(acc.y, 0.f);
            acc.z = fmaxf(acc.z, 0.f);
            acc.w = fmaxf(acc.w, 0.f);
        }
        ushort4 o;
        o.x = f2bf(acc.x); o.y = f2bf(acc.y); o.z = f2bf(acc.z); o.w = f2bf(acc.w);
        // granule = 8 ushorts (16 B); lane covers cols lane*4..lane*4+3
        int g16 = lane >> 1, h = lane & 1;
        int us  = row * 256 + ((g16 ^ (row & 7)) << 3) + h * 4;
        *reinterpret_cast<ushort4*>(&u.A[us]) = o;
    }

    // ---- phase 2: W -> bf16 register fragments (64 cols per wave, full K)
    bf16x8 bfr[4][8];   // [ni][ks]
    #pragma unroll
    for (int ni = 0; ni < 4; ++ni) {
        int col = w * 64 + ni * 16 + (lane & 15);
        const float* wrow = W + (size_t)col * CIN + (lane >> 4) * 8;
        #pragma unroll
        for (int ks = 0; ks < 8; ++ks) {
            float4 lo = *reinterpret_cast<const float4*>(wrow + ks * 32);
            float4 hi = *reinterpret_cast<const float4*>(wrow + ks * 32 + 4);
            bf16x8 f;
            f[0] = (short)f2bf(lo.x); f[1] = (short)f2bf(lo.y);
            f[2] = (short)f2bf(lo.z); f[3] = (short)f2bf(lo.w);
            f[4] = (short)f2bf(hi.x); f[5] = (short)f2bf(hi.y);
            f[6] = (short)f2bf(hi.z); f[7] = (short)f2bf(hi.w);
            bfr[ni][ks] = f;
        }
    }
    __syncthreads();   // A tile ready

    // ---- phase 3: MFMA, 256 per wave, no barriers
    f32x4 acc[4][4] = {};
    #pragma unroll
    for (int ks = 0; ks < 8; ++ks) {
        bf16x8 af[4];
        #pragma unroll
        for (int mi = 0; mi < 4; ++mi) {
            int row = mi * 16 + (lane & 15);
            int sl  = ks * 4 + (lane >> 4);
            af[mi] = *reinterpret_cast<const bf16x8*>(&u.A[row * 256 + ((sl ^ (row & 7)) << 3)]);
        }
        #pragma unroll
        for (int mi = 0; mi < 4; ++mi)
            #pragma unroll
            for (int ni = 0; ni < 4; ++ni)
                acc[mi][ni] = __builtin_amdgcn_mfma_f32_16x16x32_bf16(af[mi], bfr[ni][ks], acc[mi][ni], 0, 0, 0);
    }

    // ---- phase 4: block stats -> partial[b][1024]
    #pragma unroll
    for (int ni = 0; ni < 4; ++ni) {
        float s = 0.f, q = 0.f;
        #pragma unroll
        for (int mi = 0; mi < 4; ++mi)
            #pragma unroll
            for (int r = 0; r < 4; ++r) {
                float v = acc[mi][ni][r];
                s += v;
                q = fmaf(v, v, q);
            }
        s += __shfl_xor(s, 16); s += __shfl_xor(s, 32);
        q += __shfl_xor(q, 16); q += __shfl_xor(q, 32);
        if (lane < 16) {
            int c = w * 64 + ni * 16 + lane;
            partial[(size_t)b * 1024 + c]       = s;
            partial[(size_t)b * 1024 + 512 + c] = q;
        }
    }
    __threadfence();
    cg::this_grid().sync();

    // ---- phase 5: distributed scale/shift. Block b owns cols 2b, 2b+1.
    {
        int c = 2 * b + (t >> 8);            // threads 0-255 -> col 2b, 256-511 -> 2b+1
        int p = t & 255;                     // partial index (gridDim.x == 256)
        float S = partial[(size_t)p * 1024 + c];
        float Q = partial[(size_t)p * 1024 + 512 + c];
        #pragma unroll
        for (int off = 1; off < 64; off <<= 1) {
            S += __shfl_xor(S, off);
            Q += __shfl_xor(Q, off);
        }
        if (lane == 0) { wred[w * 2] = S; wred[w * 2 + 1] = Q; }
        __syncthreads();
        if (t == 0 || t == 256) {
            int cc   = 2 * b + (t >> 8);
            int base = (t >> 8) * 8;
            float S = wred[base + 0] + wred[base + 2] + wred[base + 4] + wred[base + 6];
            float Q = wred[base + 1] + wred[base + 3] + wred[base + 5] + wred[base + 7];
            float mean = S * invN;
            float var  = fmaf(Q, invN, -mean * mean);
            float inv  = rsqrtf(var + 1e-5f);
            float sc   = gamma[cc] * inv;
            scaleg[cc] = sc;
            shiftg[cc] = fmaf(-mean, sc, beta[cc]);
        }
    }
    __threadfence();
    cg::this_grid().sync();

    // ---- phase 6: apply BN+ReLU from live accumulators, write output
    if (t < 512) {
        float s = scaleg[t], h = shiftg[t];
        scl[t] = s; sht[t] = h; rsht[t] = fmaxf(h, 0.f);
    }
    __syncthreads();

    for (int mi = 0; mi < 4; ++mi) {
        #pragma unroll
        for (int ni = 0; ni < 4; ++ni) {
            int col = w * 64 + ni * 16 + (lane & 15);
            float s = scl[col], h = sht[col];
            int r0 = (lane >> 4) * 4;
            #pragma unroll
            for (int r = 0; r < 4; ++r)
                u.outb[r0 + r][col] = fmaxf(fmaf(acc[mi][ni][r], s, h), 0.f);
        }
        __syncthreads();
        {
            int row = t >> 5;                 // 0..15
            int j   = t & 31;
            int gr  = idx4[g0 + mi * 16 + row];   // global out row (non-empty)
            float* orow = out + (size_t)gr * COUT;
            #pragma unroll
            for (int i = 0; i < 4; ++i) {
                int c = j * 4 + i * 128;
                *reinterpret_cast<float4*>(orow + c) = *reinterpret_cast<float4*>(&u.outb[row][c]);
            }
        }
        __syncthreads();
    }

    // ---- phase 7: empty out rows -> relu(shift)
    for (int base = 0; base < orpb; base += 4) {
        int rl = base + (t >> 7);             // 4 rows per iteration
        if (inv4_l[rl] < 0) {
            int c = (t & 127) * 4;
            *reinterpret_cast<float4*>(out + (size_t)(b * orpb + rl) * COUT + c) =
                *reinterpret_cast<float4*>(&rsht[c]);
        }
    }
}

// ---------------------------------------------------------------------------
extern "C" void kernel_launch(void* const* d_in, const int* in_sizes, int n_in,
                              void* d_out, int out_size, void* d_ws, size_t ws_size,
                              hipStream_t stream) {
    const float* data   = (const float*)d_in[0];
    const float* weight = (const float*)d_in[1];
    const float* gamma  = (const float*)d_in[2];
    const float* beta   = (const float*)d_in[3];
    const int*   idx5   = (const int*)d_in[4];
    const int*   idx4   = (const int*)d_in[5];

    int n_i5 = in_sizes[4];              // 65536
    int n_i4 = in_sizes[5];              // 16384
    int rows = out_size / COUT;          // 32768
    int nblocks = n_i4 / 64;             // 256

    float* partial = (float*)d_ws;                       // nblocks*1024 floats
    float* scaleg  = partial + (size_t)nblocks * 1024;   // 512
    float* shiftg  = scaleg + COUT;                      // 512
    float* outp    = (float*)d_out;
    float  invN    = 1.0f / (float)rows;

    void* args[] = {
        (void*)&data, (void*)&weight, (void*)&gamma, (void*)&beta,
        (void*)&idx5, (void*)&n_i5, (void*)&idx4, (void*)&n_i4,
        (void*)&partial, (void*)&scaleg, (void*)&shiftg,
        (void*)&outp, (void*)&invN, (void*)&rows
    };
    hipLaunchCooperativeKernel((void*)mega_kernel, dim3(nblocks), dim3(512),
                               args, 0, stream);
}

// Round 7
// 155.070 us; speedup vs baseline: 1.7808x; 1.7808x over previous
//
#include <hip/hip_runtime.h>
#include <hip/hip_bf16.h>
#include <math.h>

#define CIN 256
#define COUT 512

typedef __attribute__((ext_vector_type(8))) short bf16x8;
typedef __attribute__((ext_vector_type(4))) float f32x4;
typedef __attribute__((ext_vector_type(4))) float f32x4v;

__device__ __forceinline__ ushort f2bf(float f) {
    union { float f; unsigned u; } x; x.f = f;
    unsigned r = x.u + 0x7FFFu + ((x.u >> 16) & 1u);   // RNE
    return (ushort)(r >> 16);
}
__device__ __forceinline__ float bf2f(ushort u) {
    union { unsigned u; float f; } x; x.u = (unsigned)u << 16; return x.f;
}

__device__ __forceinline__ int bsearch_eq(const int* __restrict__ arr, int n, int key) {
    int lo = 0, hi = n - 1;
    while (lo <= hi) {
        int mid = (lo + hi) >> 1;
        int v = arr[mid];
        if (v == key) return mid;
        if (v < key) lo = mid + 1; else hi = mid - 1;
    }
    return -1;
}

// ---------------------------------------------------------------------------
// Kernel A: three block-regions.
//   [0, nPool):          fused double max-pool, 4 waves = 4 pooled rows/block,
//                        idx5 membership via inline bsearch (R4-proven).
//   [nPool, nPool+32):   W (512x256 fp32) -> bf16 Wb.
//   [nPool+32, +64 more): inv4 scatter + gap-fill (R3-proven logic).
// ---------------------------------------------------------------------------
__global__ __launch_bounds__(256) void pool_prep_kernel(const float* __restrict__ data,
                                                        const int* __restrict__ idx5, int n_i5,
                                                        const int* __restrict__ idx4, int n_i4,
                                                        const float* __restrict__ W,
                                                        ushort* __restrict__ Wb,
                                                        ushort* __restrict__ P, int G2,
                                                        int* __restrict__ inv4, int n4) {
    const int b = blockIdx.x;
    const int nPool = G2 >> 2;
    const int t = threadIdx.x;

    if (b >= nPool) {
        int rb = b - nPool;
        if (rb < 32) {                       // W conversion: 32 blocks
            int q0 = rb * 1024 + t;
            #pragma unroll
            for (int j = 0; j < 4; ++j) {
                int i = (q0 + j * 256) * 4;
                float4 v = *reinterpret_cast<const float4*>(W + i);
                ushort4 o;
                o.x = f2bf(v.x); o.y = f2bf(v.y); o.z = f2bf(v.z); o.w = f2bf(v.w);
                *reinterpret_cast<ushort4*>(&Wb[i]) = o;
            }
        } else {                             // inv4 build: 64 blocks
            int i = (rb - 32) * 256 + t;
            if (i < n_i4) {
                int s = idx4[i];
                inv4[s] = i;
                int e = (i + 1 < n_i4) ? idx4[i + 1] : n4;
                for (int k = s + 1; k < e; ++k) inv4[k] = -1;
                if (i == 0) for (int k = 0; k < s; ++k) inv4[k] = -1;
            }
        }
        return;
    }

    __shared__ int inv5_l[32];
    if (t < 32) inv5_l[t] = bsearch_eq(idx5, n_i5, b * 32 + t);
    __syncthreads();

    const int w = t >> 6, lane = t & 63;
    const int g = b * 4 + w;                 // pooled row (one per wave)

    float4 acc = make_float4(-INFINITY, -INFINITY, -INFINITY, -INFINITY);
    bool any_empty = false;
    #pragma unroll
    for (int s = 0; s < 8; ++s) {
        int i = inv5_l[w * 8 + s];
        i = __builtin_amdgcn_readfirstlane(i);          // wave-uniform
        if (i >= 0) {
            const float* base = data + (size_t)i * (8 * CIN) + lane * 4;
            #pragma unroll
            for (int r = 0; r < 8; ++r) {
                f32x4v v = __builtin_nontemporal_load(
                    reinterpret_cast<const f32x4v*>(base + (size_t)r * CIN));
                acc.x = fmaxf(acc.x, v.x);
                acc.y = fmaxf(acc.y, v.y);
                acc.z = fmaxf(acc.z, v.z);
                acc.w = fmaxf(acc.w, v.w);
            }
        } else {
            any_empty = true;
        }
    }
    if (any_empty) {
        acc.x = fmaxf(acc.x, 0.f);
        acc.y = fmaxf(acc.y, 0.f);
        acc.z = fmaxf(acc.z, 0.f);
        acc.w = fmaxf(acc.w, 0.f);
    }
    ushort4 o;
    o.x = f2bf(acc.x); o.y = f2bf(acc.y); o.z = f2bf(acc.z); o.w = f2bf(acc.w);
    *reinterpret_cast<ushort4*>(&P[(size_t)g * CIN + lane * 4]) = o;
}

// ---------------------------------------------------------------------------
// Kernel B: bf16 MFMA GEMM + fused column stats (byte-identical to R3, proven).
// 128x128 tile / block, 256 threads (2x2 waves, 64x64/wave, 4x4 frags).
// LDS [128][64] bf16, XOR slot-swizzle (slot ^= row&7).
// ---------------------------------------------------------------------------
__global__ __launch_bounds__(256) void mfma_gemm_kernel(const ushort* __restrict__ A,
                                                        const ushort* __restrict__ B,
                                                        ushort* __restrict__ H,
                                                        float* __restrict__ partial) {
    __shared__ __align__(16) ushort Asm[128 * 64];
    __shared__ __align__(16) ushort Bsm[128 * 64];

    int t = threadIdx.x;
    int lane = t & 63;
    int wid = t >> 6;
    int wm = wid >> 1, wn = wid & 1;
    int m0 = blockIdx.x * 128, n0 = blockIdx.y * 128;

    f32x4 acc[4][4] = {};

    for (int k0 = 0; k0 < CIN; k0 += 64) {
        #pragma unroll
        for (int i = 0; i < 4; ++i) {
            int idx = i * 256 + t;          // 0..1023
            int row = idx >> 3;
            int sl  = idx & 7;
            bf16x8 av = *reinterpret_cast<const bf16x8*>(A + (size_t)(m0 + row) * CIN + k0 + sl * 8);
            bf16x8 bv = *reinterpret_cast<const bf16x8*>(B + (size_t)(n0 + row) * CIN + k0 + sl * 8);
            int ws = (sl ^ (row & 7)) * 8;
            *reinterpret_cast<bf16x8*>(&Asm[row * 64 + ws]) = av;
            *reinterpret_cast<bf16x8*>(&Bsm[row * 64 + ws]) = bv;
        }
        __syncthreads();

        #pragma unroll
        for (int ks = 0; ks < 2; ++ks) {
            bf16x8 af[4], bfr[4];
            int slog = ks * 4 + (lane >> 4);
            #pragma unroll
            for (int mi = 0; mi < 4; ++mi) {
                int row = wm * 64 + mi * 16 + (lane & 15);
                af[mi] = *reinterpret_cast<const bf16x8*>(&Asm[row * 64 + (slog ^ (row & 7)) * 8]);
            }
            #pragma unroll
            for (int ni = 0; ni < 4; ++ni) {
                int col = wn * 64 + ni * 16 + (lane & 15);
                bfr[ni] = *reinterpret_cast<const bf16x8*>(&Bsm[col * 64 + (slog ^ (col & 7)) * 8]);
            }
            #pragma unroll
            for (int mi = 0; mi < 4; ++mi)
                #pragma unroll
                for (int ni = 0; ni < 4; ++ni)
                    acc[mi][ni] = __builtin_amdgcn_mfma_f32_16x16x32_bf16(af[mi], bfr[ni], acc[mi][ni], 0, 0, 0);
        }
        __syncthreads();
    }

    // fused column stats
    float s[4], q[4];
    #pragma unroll
    for (int ni = 0; ni < 4; ++ni) {
        s[ni] = 0.f; q[ni] = 0.f;
        #pragma unroll
        for (int mi = 0; mi < 4; ++mi)
            #pragma unroll
            for (int r = 0; r < 4; ++r) {
                float v = acc[mi][ni][r];
                s[ni] += v;
                q[ni] = fmaf(v, v, q[ni]);
            }
        s[ni] += __shfl_xor(s[ni], 16); s[ni] += __shfl_xor(s[ni], 32);
        q[ni] += __shfl_xor(q[ni], 16); q[ni] += __shfl_xor(q[ni], 32);
    }
    float* redS = (float*)Asm;
    float* redQ = redS + 256;
    if (lane < 16) {
        #pragma unroll
        for (int ni = 0; ni < 4; ++ni) {
            int c = wn * 64 + ni * 16 + lane;
            redS[wm * 128 + c] = s[ni];
            redQ[wm * 128 + c] = q[ni];
        }
    }
    __syncthreads();
    if (t < 128) {
        float S = redS[t] + redS[128 + t];
        float Q = redQ[t] + redQ[128 + t];
        partial[(size_t)blockIdx.x * 1024 + blockIdx.y * 128 + t]       = S;
        partial[(size_t)blockIdx.x * 1024 + 512 + blockIdx.y * 128 + t] = Q;
    }

    // H write (bf16)
    #pragma unroll
    for (int mi = 0; mi < 4; ++mi) {
        #pragma unroll
        for (int ni = 0; ni < 4; ++ni) {
            int col   = n0 + wn * 64 + ni * 16 + (lane & 15);
            int rbase = m0 + wm * 64 + mi * 16 + (lane >> 4) * 4;
            #pragma unroll
            for (int r = 0; r < 4; ++r)
                H[(size_t)(rbase + r) * COUT + col] = f2bf(acc[mi][ni][r]);
        }
    }
}

// ---------------------------------------------------------------------------
// Kernel C: finalize BN scale/shift (R3, proven)
// ---------------------------------------------------------------------------
__global__ __launch_bounds__(256) void bn_finalize_kernel(const float* __restrict__ partial, int nparts,
                                                          const float* __restrict__ gamma,
                                                          const float* __restrict__ beta,
                                                          float* __restrict__ scale,
                                                          float* __restrict__ shift,
                                                          float invN) {
    int c = blockIdx.x * blockDim.x + threadIdx.x;
    if (c >= COUT) return;
    float s = 0.f, q = 0.f;
    for (int p = 0; p < nparts; ++p) {
        s += partial[(size_t)p * 1024 + c];
        q += partial[(size_t)p * 1024 + 512 + c];
    }
    float mean = s * invN;
    float var  = fmaf(q, invN, -mean * mean);
    float inv  = rsqrtf(var + 1e-5f);
    float sc   = gamma[c] * inv;
    scale[c] = sc;
    shift[c] = fmaf(-mean, sc, beta[c]);
}

// ---------------------------------------------------------------------------
// Kernel D: normalize + relu + scatter (R3, proven; H is bf16)
// ---------------------------------------------------------------------------
__global__ __launch_bounds__(256) void out_kernel(const ushort* __restrict__ H,
                                                  const int* __restrict__ inv4,
                                                  const float* __restrict__ scale,
                                                  const float* __restrict__ shift,
                                                  float* __restrict__ out, int rows) {
    int t = blockIdx.x * blockDim.x + threadIdx.x;
    int m = t >> 7;
    int qd = t & 127;
    if (m >= rows) return;
    int c = qd * 4;
    int j = inv4[m];
    float4 sc = *reinterpret_cast<const float4*>(&scale[c]);
    float4 sh = *reinterpret_cast<const float4*>(&shift[c]);
    float4 r;
    if (j >= 0) {
        ushort4 h = *reinterpret_cast<const ushort4*>(&H[(size_t)j * COUT + c]);
        r.x = fmaxf(fmaf(bf2f(h.x), sc.x, sh.x), 0.f);
        r.y = fmaxf(fmaf(bf2f(h.y), sc.y, sh.y), 0.f);
        r.z = fmaxf(fmaf(bf2f(h.z), sc.z, sh.z), 0.f);
        r.w = fmaxf(fmaf(bf2f(h.w), sc.w, sh.w), 0.f);
    } else {
        r.x = fmaxf(sh.x, 0.f);
        r.y = fmaxf(sh.y, 0.f);
        r.z = fmaxf(sh.z, 0.f);
        r.w = fmaxf(sh.w, 0.f);
    }
    *reinterpret_cast<float4*>(&out[(size_t)m * COUT + c]) = r;
}

// ---------------------------------------------------------------------------
extern "C" void kernel_launch(void* const* d_in, const int* in_sizes, int n_in,
                              void* d_out, int out_size, void* d_ws, size_t ws_size,
                              hipStream_t stream) {
    const float* data   = (const float*)d_in[0];
    const float* weight = (const float*)d_in[1];
    const float* gamma  = (const float*)d_in[2];
    const float* beta   = (const float*)d_in[3];
    const int*   idx5   = (const int*)d_in[4];
    const int*   idx4   = (const int*)d_in[5];

    const int n_i5 = in_sizes[4];        // 65536
    const int n_i4 = in_sizes[5];        // 16384
    const int G2   = n_i4;
    const int rows = out_size / COUT;    // 32768
    const int M    = G2;                 // 16384
    const int MB   = M / 128;            // 128 m-tiles

    // workspace layout
    char* w = (char*)d_ws;
    ushort* P      = (ushort*)w;                        w += (size_t)G2 * CIN * sizeof(ushort);    // 8 MiB
    ushort* H      = (ushort*)w;                        w += (size_t)G2 * COUT * sizeof(ushort);   // 16 MiB
    ushort* Wb     = (ushort*)w;                        w += (size_t)COUT * CIN * sizeof(ushort);  // 0.25 MiB
    float* partial = (float*)w;                         w += (size_t)MB * 1024 * sizeof(float);    // 512 KiB
    float* scale   = (float*)w;                         w += COUT * sizeof(float);
    float* shift   = (float*)w;                         w += COUT * sizeof(float);
    int*   inv4    = (int*)w;                           w += (size_t)rows * sizeof(int);           // 128 KiB

    // A: pool (G2/4 blocks) + W->bf16 (32 blocks) + inv4 build (64 blocks)
    pool_prep_kernel<<<G2 / 4 + 32 + (n_i4 + 255) / 256, 256, 0, stream>>>(
        data, idx5, n_i5, idx4, n_i4, weight, Wb, P, G2, inv4, rows);

    // B: MFMA GEMM + fused stats
    {
        dim3 grid(MB, COUT / 128);
        mfma_gemm_kernel<<<grid, 256, 0, stream>>>(P, Wb, H, partial);
    }
    // C: finalize BN scale/shift
    bn_finalize_kernel<<<2, 256, 0, stream>>>(partial, MB, gamma, beta, scale, shift,
                                              1.0f / (float)rows);
    // D: normalize + relu + scatter
    out_kernel<<<((size_t)rows * 128 + 255) / 256, 256, 0, stream>>>(H, inv4, scale, shift,
                                                                     (float*)d_out, rows);
}